// Round 7
// baseline (233.393 us; speedup 1.0000x reference)
//
#include <hip/hip_runtime.h>
#include <hip/hip_bf16.h>
#include <math.h>

typedef short bf16x8 __attribute__((ext_vector_type(8)));
typedef float f32x4 __attribute__((ext_vector_type(4)));

#define MFMA16x16(a, b, c) __builtin_amdgcn_mfma_f32_16x16x32_bf16(a, b, c, 0, 0, 0)

__device__ __forceinline__ float silu_f(float v) { return v / (1.0f + __expf(-v)); }
// XOR swizzle for [row][128B] LDS tiles
__device__ __forceinline__ int swz128(int b) { return b ^ (((b >> 7) & 7) << 4); }

__device__ __forceinline__ unsigned short f2bf(float f) {  // RNE f32->bf16
  union { float f; unsigned u; } x; x.f = f;
  unsigned r = x.u + 0x7fffu + ((x.u >> 16) & 1u);
  return (unsigned short)(r >> 16);
}
__device__ __forceinline__ float bf2f(unsigned short h) {
  union { unsigned u; float f; } x; x.u = ((unsigned)h) << 16;
  return x.f;
}

__device__ __forceinline__ void gload_lds16(const void* g, void* l) {
  __builtin_amdgcn_global_load_lds((__attribute__((address_space(1))) unsigned int*)g,
                                   (__attribute__((address_space(3))) unsigned int*)l,
                                   16, 0, 0);
}

// ---------- offsets decode + balanced tile list + token->(b,pos) table ----------
__global__ void k_prep(const int* __restrict__ raw, int Bp1, int* __restrict__ offs,
                       int* __restrict__ tiles, int qtmax, int* __restrict__ tok2bp, int T) {
  __shared__ int s_off[128], s_nt[128], s_cnt[128], s_base[128];
  int t = threadIdx.x;
  int B = Bp1 - 1;
  bool is64 = (raw[3] == 0);
  if (t < Bp1) { int v = is64 ? raw[2 * t] : raw[t]; offs[t] = v; s_off[t] = v; }
  __syncthreads();
  if (t < B) s_nt[t] = (s_off[t + 1] - s_off[t] + 31) >> 5;
  __syncthreads();
  if (t < qtmax) {
    int c = 0;
    for (int b = 0; b < B; ++b) c += (t < s_nt[b]) ? 1 : 0;
    s_cnt[t] = c;
  }
  __syncthreads();
  if (t < qtmax) {
    int basev = 0;
    for (int q2 = t + 1; q2 < qtmax; ++q2) basev += s_cnt[q2];
    s_base[t] = basev;
  }
  __syncthreads();
  if (t == 0) tiles[0] = (s_base[0] + s_cnt[0]) * 8;  // total wave units (x8 heads)
  for (int i = t; i < qtmax * B; i += 256) {
    int qt = i / B, b = i - qt * B;
    if (qt < s_nt[b]) {
      int rank = 0;
      for (int b2 = 0; b2 < b; ++b2) rank += (qt < s_nt[b2]) ? 1 : 0;
      tiles[1 + s_base[qt] + rank] = (b << 16) | qt;
    }
  }
  // token -> (b, pos): b = #{j: offs[j+1] <= i}
  for (int i = t; i < T; i += 256) {
    int b = 0;
    for (int j = 0; j < B; ++j) b += (s_off[j + 1] <= i) ? 1 : 0;
    tok2bp[i] = (b << 16) | (i - s_off[b]);
  }
}

// ---------- zero-fill kC/vT padding tails (pos in [len, npad64)) ----------
__global__ __launch_bounds__(256) void k_zfill(const int* __restrict__ offs,
                                               unsigned short* __restrict__ kC,
                                               unsigned short* __restrict__ vT, int ns) {
  int bh = blockIdx.x, b = bh >> 3;
  int len = offs[b + 1] - offs[b];
  int npad = (len + 63) & ~63;
  int tail = npad - len;
  if (tail == 0) return;
  int tid = threadIdx.x;
  unsigned short* kc = kC + (size_t)bh * ns * 64 + (size_t)len * 64;
  for (int i = tid; i < tail * 8; i += 256) {
    uint4 z = {0u, 0u, 0u, 0u};
    *(uint4*)(kc + i * 8) = z;
  }
  unsigned short* vt = vT + (size_t)bh * 64 * ns;
  for (int i = tid; i < 64 * tail; i += 256) {
    int d = i / tail, c = len + (i - d * tail);
    vt[(size_t)d * ns + c] = 0;
  }
}

// ---------- uvqk (512x2048 f32) -> uvqkT (2048x512 bf16), transposed ----------
__global__ __launch_bounds__(256) void k_conv_uvqkT(const float* __restrict__ uvqk,
                                                    unsigned short* __restrict__ uvqkT) {
  __shared__ float tile[32][33];
  int n0 = blockIdx.x * 32, k0 = blockIdx.y * 32;
  int tx = threadIdx.x & 31;
  int ty = threadIdx.x >> 5;
#pragma unroll
  for (int i = 0; i < 4; ++i)
    tile[ty + 8 * i][tx] = uvqk[(size_t)(k0 + ty + 8 * i) * 2048 + n0 + tx];
  __syncthreads();
#pragma unroll
  for (int i = 0; i < 4; ++i) {
    int nn = ty + 8 * i;
    uvqkT[(size_t)(n0 + nn) * 512 + k0 + tx] = f2bf(tile[tx][nn]);
  }
}

__global__ __launch_bounds__(256) void k_conv_bf16(const float* __restrict__ in,
                                                   unsigned short* __restrict__ out, int n) {
  int i = blockIdx.x * 256 + threadIdx.x;
  if (i < n) out[i] = f2bf(in[i]);
}

// ---------- LayerNorm(x) -> bf16, one wave per 512-row ----------
__global__ __launch_bounds__(256) void k_ln_x(const float* __restrict__ x,
                                              unsigned short* __restrict__ normed, int T) {
  int lane = threadIdx.x & 63, wid = threadIdx.x >> 6;
  int row = blockIdx.x * 4 + wid;
  if (row >= T) return;
  const float4* xr = (const float4*)(x + (size_t)row * 512);
  float4 a = xr[lane * 2], b = xr[lane * 2 + 1];
  float s = a.x + a.y + a.z + a.w + b.x + b.y + b.z + b.w;
  float s2 = a.x * a.x + a.y * a.y + a.z * a.z + a.w * a.w +
             b.x * b.x + b.y * b.y + b.z * b.z + b.w * b.w;
#pragma unroll
  for (int m = 1; m < 64; m <<= 1) { s += __shfl_xor(s, m); s2 += __shfl_xor(s2, m); }
  float mean = s * (1.0f / 512.0f);
  float var = s2 * (1.0f / 512.0f) - mean * mean;
  float rstd = rsqrtf(var + 1e-6f);
  float v[8] = {a.x, a.y, a.z, a.w, b.x, b.y, b.z, b.w};
  unsigned short o[8];
#pragma unroll
  for (int j = 0; j < 8; ++j) o[j] = f2bf((v[j] - mean) * rstd);
  *(uint4*)(normed + (size_t)row * 512 + lane * 8) = *(uint4*)o;
}

// ---------- o_input = u * LayerNorm(attn_bf16) -> bf16 ----------
__global__ __launch_bounds__(256) void k_ln_mul_u(const unsigned short* __restrict__ attnb,
                                                  const unsigned short* __restrict__ mmu,
                                                  unsigned short* __restrict__ oin, int T) {
  int lane = threadIdx.x & 63, wid = threadIdx.x >> 6;
  int row = blockIdx.x * 4 + wid;
  if (row >= T) return;
  uint4 av = *(const uint4*)(attnb + (size_t)row * 512 + lane * 8);
  const unsigned short* ae = (const unsigned short*)&av;
  float v[8];
#pragma unroll
  for (int j = 0; j < 8; ++j) v[j] = bf2f(ae[j]);
  float s = 0.f, s2 = 0.f;
#pragma unroll
  for (int j = 0; j < 8; ++j) { s += v[j]; s2 += v[j] * v[j]; }
#pragma unroll
  for (int m = 1; m < 64; m <<= 1) { s += __shfl_xor(s, m); s2 += __shfl_xor(s2, m); }
  float mean = s * (1.0f / 512.0f);
  float var = s2 * (1.0f / 512.0f) - mean * mean;
  float rstd = rsqrtf(var + 1e-6f);
  uint4 ub = *(const uint4*)(mmu + (size_t)row * 512 + lane * 8);
  const unsigned short* us = (const unsigned short*)&ub;
  unsigned short o[8];
#pragma unroll
  for (int j = 0; j < 8; ++j) o[j] = f2bf((v[j] - mean) * rstd * bf2f(us[j]));
  *(uint4*)(oin + (size_t)row * 512 + lane * 8) = *(uint4*)o;
}

// ---------- 8-wave 128x128 MFMA GEMM, BK=64, Bt is (N,K) row-major ----------
// 512 thr = 8 waves (2M x 4N), wave-tile 64x32: acc[4][2] (32 AGPR) -> high occupancy.
// Staging: wave w owns rows [w*16,(w+1)*16); TWO gload_lds per matrix per K-tile
// (rows srow and srow+8; 1KB each) -- full 16KB tile coverage (R5 bug: only half).
// MODE 0 (GEMM1): silu -> scatter to {mmu, vT, qC, kC} per 512-col region.
// MODE 1 (GEMM2): + bias + xres -> f32 Cout.
template <int MODE>
__global__ __launch_bounds__(512, 4) void k_gemm8w(
    const unsigned short* __restrict__ A, const unsigned short* __restrict__ Bt,
    int M, int K, int Nn, int ntn,
    unsigned short* __restrict__ mmu, unsigned short* __restrict__ qC,
    unsigned short* __restrict__ kC, unsigned short* __restrict__ vT,
    const int* __restrict__ tok2bp, int ns,
    float* __restrict__ Cout, const float* __restrict__ bias, const float* __restrict__ xres) {
  __shared__ __align__(16) char lds[32768];
  char* const ldsA = lds;
  char* const ldsB = lds + 16384;
  int bid = blockIdx.x;
  int mt = bid / ntn, nt = bid - mt * ntn;
  int m0 = mt * 128, n0 = nt * 128;
  int tid = threadIdx.x, lane = tid & 63, wid = tid >> 6;
  int wm = wid >> 2, wn = wid & 3;  // 2M x 4N waves
  int fr = lane & 15, fq = lane >> 4;
  f32x4 acc[4][2] = {};
  int nK = K >> 6;
  // staging: lane -> row srow=(wid*16 + lane>>3) and srow+8, seg lane&7 (16B)
  int srow = wid * 16 + (lane >> 3);
  int scb = (((lane & 7) ^ (lane >> 3)) << 4);  // pre-swizzled source byte col
  char* const dstA0 = ldsA + wid * 2048;        // wave-uniform; HW adds lane*16
  char* const dstA1 = ldsA + wid * 2048 + 1024;
  char* const dstB0 = ldsB + wid * 2048;
  char* const dstB1 = ldsB + wid * 2048 + 1024;
  int ar0 = m0 + srow; if (ar0 >= M) ar0 = M - 1;
  int ar1 = m0 + srow + 8; if (ar1 >= M) ar1 = M - 1;
  const char* gA0 = (const char*)(A + (size_t)ar0 * K) + scb;
  const char* gA1 = (const char*)(A + (size_t)ar1 * K) + scb;
  const char* gB0 = (const char*)(Bt + (size_t)(n0 + srow) * K) + scb;
  const char* gB1 = (const char*)(Bt + (size_t)(n0 + srow + 8) * K) + scb;

  for (int kt = 0; kt < nK; ++kt) {
    gload_lds16(gA0 + (kt << 7), dstA0);
    gload_lds16(gA1 + (kt << 7), dstA1);
    gload_lds16(gB0 + (kt << 7), dstB0);
    gload_lds16(gB1 + (kt << 7), dstB1);
    __syncthreads();
    bf16x8 a[4][2], b[2][2];
#pragma unroll
    for (int mi = 0; mi < 4; ++mi) {
      int r = wm * 64 + mi * 16 + fr;
#pragma unroll
      for (int kk = 0; kk < 2; ++kk)
        a[mi][kk] = *(const bf16x8*)(ldsA + swz128(r * 128 + kk * 64 + fq * 16));
    }
#pragma unroll
    for (int ni = 0; ni < 2; ++ni) {
      int r = wn * 32 + ni * 16 + fr;
#pragma unroll
      for (int kk = 0; kk < 2; ++kk)
        b[ni][kk] = *(const bf16x8*)(ldsB + swz128(r * 128 + kk * 64 + fq * 16));
    }
#pragma unroll
    for (int mi = 0; mi < 4; ++mi)
#pragma unroll
      for (int ni = 0; ni < 2; ++ni) {
        acc[mi][ni] = MFMA16x16(a[mi][0], b[ni][0], acc[mi][ni]);
        acc[mi][ni] = MFMA16x16(a[mi][1], b[ni][1], acc[mi][ni]);
      }
    __syncthreads();
  }
  int c0 = n0 + wn * 32;
#pragma unroll
  for (int mi = 0; mi < 4; ++mi) {
#pragma unroll
    for (int j = 0; j < 4; ++j) {
      int r = m0 + wm * 64 + mi * 16 + fq * 4 + j;
      if (r >= M) continue;
      if (MODE == 0) {
        int bp = tok2bp[r];
        int bb = bp >> 16, pos = bp & 0xffff;
#pragma unroll
        for (int ni = 0; ni < 2; ++ni) {
          int c = c0 + ni * 16 + fr;
          unsigned short bf = f2bf(silu_f(acc[mi][ni][j]));
          int reg = c >> 9;             // 0:u 1:v 2:q 3:k (512-aligned regions)
          int h = (c >> 6) & 7, d = c & 63;
          size_t bh = (size_t)(bb * 8 + h);
          if (reg == 0) mmu[(size_t)r * 512 + c] = bf;
          else if (reg == 1) vT[(bh * 64 + d) * ns + pos] = bf;
          else if (reg == 2) qC[(bh * ns + pos) * 64 + d] = bf;
          else kC[(bh * ns + pos) * 64 + d] = bf;
        }
      } else {
#pragma unroll
        for (int ni = 0; ni < 2; ++ni) {
          int c = c0 + ni * 16 + fr;
          Cout[(size_t)r * Nn + c] = acc[mi][ni][j] + bias[c] + xres[(size_t)r * 512 + c];
        }
      }
    }
  }
}

// ---------- jagged causal SiLU-attention: flat balanced wave units ----------
__global__ __launch_bounds__(256) void k_attn3(const unsigned short* __restrict__ qC,
                                               const unsigned short* __restrict__ kC,
                                               const unsigned short* __restrict__ vT,
                                               const int* __restrict__ offs,
                                               const int* __restrict__ tiles,
                                               unsigned short* __restrict__ attnb,
                                               float inv_n, int ns) {
  __shared__ __align__(16) char sP[16384];  // 4KB per wave: P [32 q][64 s] bf16, swz128
  int tid = threadIdx.x, lane = tid & 63, wid = tid >> 6;
  int w = blockIdx.x * 4 + wid;
  if (w >= tiles[0]) return;  // wave-uniform exit (no barriers in kernel)
  int e = tiles[1 + (w >> 3)];
  int h = w & 7;
  int b = e >> 16, qt = e & 0xffff;
  int bh = b * 8 + h;
  int off = offs[b], len = offs[b + 1] - offs[b];
  int qb = qt * 32;
  int fr = lane & 15, fq = lane >> 4;
  const unsigned short* qp = qC + (size_t)bh * ns * 64;
  const unsigned short* kcp = kC + (size_t)bh * ns * 64;
  const unsigned short* vtp = vT + (size_t)bh * 64 * ns;
  bf16x8 aq[2][2];  // Q frags: row q = mi*16+fr, k = kk*32+fq*8+j
#pragma unroll
  for (int mi = 0; mi < 2; ++mi) {
    int qr = qb + mi * 16 + fr; if (qr >= len) qr = len - 1;
#pragma unroll
    for (int kk = 0; kk < 2; ++kk)
      aq[mi][kk] = *(const bf16x8*)(qp + (size_t)qr * 64 + kk * 32 + fq * 8);
  }
  f32x4 accO[2][4] = {};
  char* pw = sP + wid * 4096;
  int nkt = (qb >> 6) + 1;
  for (int kt = 0; kt < nkt; ++kt) {
    int s0 = kt << 6;
    f32x4 sacc[2][4] = {};
#pragma unroll
    for (int ni = 0; ni < 4; ++ni) {
      const unsigned short* kr = kcp + (size_t)(s0 + ni * 16 + fr) * 64 + fq * 8;
      bf16x8 k0 = *(const bf16x8*)kr;
      bf16x8 k1 = *(const bf16x8*)(kr + 32);
#pragma unroll
      for (int mi = 0; mi < 2; ++mi) {
        sacc[mi][ni] = MFMA16x16(aq[mi][0], k0, sacc[mi][ni]);
        sacc[mi][ni] = MFMA16x16(aq[mi][1], k1, sacc[mi][ni]);
      }
    }
    bf16x8 vf[4][2];
#pragma unroll
    for (int nd = 0; nd < 4; ++nd)
#pragma unroll
      for (int kk = 0; kk < 2; ++kk)
        vf[nd][kk] = *(const bf16x8*)(vtp + (size_t)(nd * 16 + fr) * ns + s0 + kk * 32 + fq * 8);
#pragma unroll
    for (int mi = 0; mi < 2; ++mi)
#pragma unroll
      for (int ni = 0; ni < 4; ++ni)
#pragma unroll
        for (int j = 0; j < 4; ++j) {
          int pq = qb + mi * 16 + fq * 4 + j;
          int ps = s0 + ni * 16 + fr;
          float v = (ps <= pq) ? silu_f(sacc[mi][ni][j]) * inv_n : 0.0f;
          *(unsigned short*)(pw + swz128((mi * 16 + fq * 4 + j) * 128 + (ni * 16 + fr) * 2)) =
              f2bf(v);
        }
    bf16x8 pa[2][2];
#pragma unroll
    for (int mi = 0; mi < 2; ++mi) {
      pa[mi][0] = *(const bf16x8*)(pw + swz128((mi * 16 + fr) * 128 + fq * 16));
      pa[mi][1] = *(const bf16x8*)(pw + swz128((mi * 16 + fr) * 128 + 64 + fq * 16));
    }
#pragma unroll
    for (int nd = 0; nd < 4; ++nd)
#pragma unroll
      for (int mi = 0; mi < 2; ++mi) {
        accO[mi][nd] = MFMA16x16(pa[mi][0], vf[nd][0], accO[mi][nd]);
        accO[mi][nd] = MFMA16x16(pa[mi][1], vf[nd][1], accO[mi][nd]);
      }
  }
#pragma unroll
  for (int mi = 0; mi < 2; ++mi)
#pragma unroll
    for (int nd = 0; nd < 4; ++nd)
#pragma unroll
      for (int j = 0; j < 4; ++j) {
        int pq = qb + mi * 16 + fq * 4 + j;
        if (pq < len)
          attnb[(size_t)(off + pq) * 512 + h * 64 + nd * 16 + fr] = f2bf(accO[mi][nd][j]);
      }
}

extern "C" void kernel_launch(void* const* d_in, const int* in_sizes, int n_in,
                              void* d_out, int out_size, void* d_ws, size_t ws_size,
                              hipStream_t stream) {
  const float* x = (const float*)d_in[0];
  const int* xoff = (const int*)d_in[1];
  const float* uvqk = (const float*)d_in[3];
  const float* ow = (const float*)d_in[4];
  const float* obias = (const float*)d_in[5];

  const int D = 512;
  int T = in_sizes[0] / D;
  int B = in_sizes[1] - 1;
  int nm = 1;
  while ((long long)nm * nm < (long long)in_sizes[2]) nm <<= 1;  // mask dim (1024)
  int qtmax = nm / 32;

  char* w = (char*)d_ws;
  size_t p = 0;
  auto alloc = [&](size_t bytes) { size_t r = p; p += (bytes + 255) & ~(size_t)255; return r; };
  int* offs = (int*)(w + alloc(sizeof(int) * (size_t)(B + 1)));
  int* tiles = (int*)(w + alloc(sizeof(int) * (size_t)(1 + B * qtmax)));
  int* tok2bp = (int*)(w + alloc(sizeof(int) * (size_t)T));
  unsigned short* normed = (unsigned short*)(w + alloc((size_t)T * 512 * 2));
  unsigned short* mmu = (unsigned short*)(w + alloc((size_t)T * 512 * 2));
  unsigned short* attnb = (unsigned short*)(w + alloc((size_t)T * 512 * 2));
  unsigned short* oin = (unsigned short*)(w + alloc((size_t)T * 512 * 2));
  unsigned short* uvqkT = (unsigned short*)(w + alloc((size_t)2048 * 512 * 2));
  unsigned short* owb = (unsigned short*)(w + alloc((size_t)512 * 512 * 2));
  unsigned short* qC = (unsigned short*)(w + alloc((size_t)B * 8 * (size_t)nm * 64 * 2));
  unsigned short* kC = (unsigned short*)(w + alloc((size_t)B * 8 * (size_t)nm * 64 * 2));
  unsigned short* vT = (unsigned short*)(w + alloc((size_t)B * 8 * 64 * (size_t)nm * 2));

  k_prep<<<1, 256, 0, stream>>>(xoff, B + 1, offs, tiles, qtmax, tok2bp, T);
  k_zfill<<<B * 8, 256, 0, stream>>>(offs, kC, vT, nm);
  k_conv_uvqkT<<<dim3(64, 16), 256, 0, stream>>>(uvqk, uvqkT);
  k_conv_bf16<<<1024, 256, 0, stream>>>(ow, owb, 512 * 512);
  k_ln_x<<<(T + 3) / 4, 256, 0, stream>>>(x, normed, T);
  int ntm = (T + 127) / 128;
  k_gemm8w<0><<<ntm * 16, 512, 0, stream>>>(normed, uvqkT, T, 512, 2048, 16,
                                            mmu, qC, kC, vT, tok2bp, nm,
                                            nullptr, nullptr, nullptr);
  int maxw = B * qtmax * 8;
  k_attn3<<<(maxw + 3) / 4, 256, 0, stream>>>(qC, kC, vT, offs, tiles, attnb,
                                              1.0f / (float)nm, nm);
  k_ln_mul_u<<<(T + 3) / 4, 256, 0, stream>>>(attnb, mmu, oin, T);
  k_gemm8w<1><<<ntm * 4, 512, 0, stream>>>(oin, owb, T, 512, 512, 4,
                                           nullptr, nullptr, nullptr, nullptr, nullptr, nm,
                                           (float*)d_out, obias, x);
}